// Round 17
// baseline (6465.573 us; speedup 1.0000x reference)
//
#include <hip/hip_runtime.h>

typedef unsigned long long ull;
typedef unsigned int uint;
typedef unsigned short ushort;
typedef float  f32x2 __attribute__((ext_vector_type(2)));
typedef float  f32x4 __attribute__((ext_vector_type(4)));
typedef short  s16x8 __attribute__((ext_vector_type(8)));
typedef uint   u32x4 __attribute__((ext_vector_type(4)));

constexpr int BATCH = 256;
constexpr int TT    = 1024;
constexpr int HD    = 512;
constexpr int A_SZ    = 8 * HD * 2;          // 8192 B per A split (bf16 [8][512])
constexpr int ZB_OFF  = 3 * A_SZ;            // 24576: zero block (padded A rows 8..15)
constexpr int LDS_USED_A = ZB_OFF + 256;     // 24832
constexpr int BLO_OFF = LDS_USED_A;          // B lo-split [64][512] bf16 (65536)
constexpr int SCR_OFF = BLO_OFF + 64 * HD * 2;   // 90368: K-reduce scratch
constexpr int SCR_SZ  = 16 * 64 * 16;        // 16384 per buffer (16 slots x 64 lanes x 16B)
constexpr int LDS_BYTES = SCR_OFF + 2 * SCR_SZ;  // 123136 -> 1 wg/CU
constexpr uint SENT = 0x80000000u;           // -0.0f, unreachable by sanitized relu out

__device__ __forceinline__ ushort f2bf(float f) {
    uint u = __float_as_uint(f);
    return (ushort)((u + 0x7fffu + ((u >> 16) & 1u)) >> 16);
}
__device__ __forceinline__ float bf2f(ushort b) {
    return __uint_as_float((uint)b << 16);
}
__device__ __forceinline__ void split3(float v, ushort& h, ushort& m, ushort& l) {
    h = f2bf(v);
    float r1 = v - bf2f(h);
    m = f2bf(r1);
    float r2 = r1 - bf2f(m);
    l = f2bf(r2);
}
// R7-validated swizzle within a [rows][512] bf16 region (writer/reader consistent)
__device__ __forceinline__ uint swz(uint r, uint k) {
    return (r * 1024u + k * 2u) ^ (((r ^ (k >> 6)) & 7u) << 4);
}
// lgkm-only barrier: orders LDS across waves WITHOUT draining vmcnt
__device__ __forceinline__ void bar_lds() {
    asm volatile("s_waitcnt lgkmcnt(0)" ::: "memory");
    __builtin_amdgcn_s_barrier();
}

__global__ void __launch_bounds__(256, 1)
fill_kernel(uint* __restrict__ out)   // arm out[1..1024] with sentinel
{
    const size_t n = (size_t)TT * BATCH * HD / 4;
    uint* base = out + (size_t)BATCH * HD;
    u32x4 s = {SENT, SENT, SENT, SENT};
    for (size_t j = (size_t)blockIdx.x * 256 + threadIdx.x; j < n;
         j += (size_t)gridDim.x * 256)
        *(u32x4*)(base + j * 4) = s;
}

__global__ void __launch_bounds__(256, 1)
init_kernel(float* __restrict__ out)  // out[0] = h0 pattern
{
    int base = (blockIdx.x * 256 + threadIdx.x) * 4;
    int k = base & 511;
    f32x4 v = {0.f, 0.f, 0.f, 0.f};
    if (k == 0 || k == 256) v.x = 1.f;
    *(f32x4*)(out + base) = v;
}

__global__ void __launch_bounds__(256, 1)
rnn_ksplit_kernel(const float* __restrict__ x, const float* __restrict__ Wh,
                  const float* __restrict__ Wx, const float* __restrict__ bx,
                  float* __restrict__ out)
{
    extern __shared__ char lds[];
    char* Ah  = lds;
    char* Am  = lds + A_SZ;
    char* Al  = lds + 2 * A_SZ;
    char* ZB  = lds + ZB_OFF;
    char* Blo = lds + BLO_OFF;

    const int tid  = threadIdx.x;
    const int wid  = blockIdx.x;
    const int gb   = wid & 31;        // batch group (8 rows)
    const int gh   = wid >> 5;        // h-slice group (64 outs)
    const int lane = tid & 63;
    const int wv   = tid >> 6;        // wave = K-QUARTER (kt 4wv..4wv+3, chunks 2wv,2wv+1)
    const int m    = lane & 15;       // frag row (A) / col (B)
    const int koct = lane >> 4;
    const bool mhi = (m >= 8);        // padded A rows -> zero block

    // ---- prologue: zero A region + ZB; h0 ones ----
    for (int i = tid; i < LDS_USED_A / 4; i += 256) ((uint*)lds)[i] = 0u;
    __syncthreads();
    if (tid < 16) {
        uint r = (uint)(tid & 7), k = (uint)((tid >> 3) * 256);
        *(uint*)(Ah + swz(r, k)) = 0x3F80u;   // bf16 1.0 (k=0 -> wave0 range, 256 -> wave2)
    }

    // ---- B: hi/mid in regs [nt][j] (128 VGPR), lo -> Blo. Wave w covers its 4 kt
    //      for ALL 4 nt; union over waves fills Blo[64][512]. ----
    s16x8 bh[4][4], bm[4][4];
    #pragma unroll
    for (int j = 0; j < 4; ++j) {
        const int ktg = wv * 4 + j;
        #pragma unroll
        for (int nt = 0; nt < 4; ++nt) {
            const int colW = gh * 64 + nt * 16 + m;
            const float* p = Wh + (size_t)colW * HD + ktg * 32 + koct * 8;
            f32x4 v0 = *(const f32x4*)p;
            f32x4 v1 = *(const f32x4*)(p + 4);
            float vv[8] = {v0.x, v0.y, v0.z, v0.w, v1.x, v1.y, v1.z, v1.w};
            s16x8 th, tm, tl;
            #pragma unroll
            for (int q = 0; q < 8; ++q) {
                ushort hh, mm, ll; split3(vv[q], hh, mm, ll);
                th[q] = (short)hh; tm[q] = (short)mm; tl[q] = (short)ll;
            }
            bh[nt][j] = th; bm[nt][j] = tm;
            *(s16x8*)(Blo + swz((uint)(nt * 16 + m), (uint)(ktg * 32 + koct * 8))) = tl;
        }
    }

    const int  col  = gh * 64 + wv * 16 + m;       // epilogue col (this wave reduces nt=wv)
    const f32x2 wxv = *(const f32x2*)(Wx + col * 2);
    const float bq  = bx[col];
    const bool doEp = (lane < 32);
    const int  r0   = koct * 4;                    // C/D: row = koct*4 + reg (m89)

    // ---- exchange mapping: wave-local. lane -> (row, 16-col strip of own 2 chunks) ----
    const int exr = lane >> 3;                     // 0..7
    const int cb  = wv * 128 + (lane & 7) * 16;    // col base (16 cols = 8 ull)
    const size_t rowoff = (size_t)(gb * 8 + exr) * HD + cb;

    ull pv[8];

    __syncthreads();   // A (h0) + Blo ready

    for (int t = 0; t < TT; ++t) {
        f32x2 xr[4];
        if (doEp) {
            #pragma unroll
            for (int r = 0; r < 4; ++r)
                xr[r] = *(const f32x2*)(x + ((size_t)(gb * 8 + r0 + r) * TT + t) * 2);
        }

        // ---- wait own 2 chunks of h_t (polls issued last iter); split -> own A region.
        //      Own-wave write->read: no barrier needed (lgkmcnt ordering). ----
        if (t > 0) {
            const float* sh = out + (size_t)t * BATCH * HD + rowoff;
            for (;;) {
                bool ok = true;
                #pragma unroll
                for (int j = 0; j < 8; ++j)
                    if ((uint)pv[j] == SENT || (uint)(pv[j] >> 32) == SENT) ok = false;
                if (ok) break;
                __builtin_amdgcn_s_sleep(1);
                #pragma unroll
                for (int j = 0; j < 8; ++j)
                    pv[j] = __hip_atomic_load((const ull*)(sh + 2 * j),
                                              __ATOMIC_RELAXED, __HIP_MEMORY_SCOPE_AGENT);
            }
            #pragma unroll
            for (int j = 0; j < 8; ++j) {
                union { ull u; f32x2 f; } cu; cu.u = pv[j];
                ushort h0, m0, l0, h1, m1, l1;
                split3(cu.f.x, h0, m0, l0);
                split3(cu.f.y, h1, m1, l1);
                uint off = swz((uint)exr, (uint)(cb + 2 * j));
                *(uint*)(Ah + off) = (uint)h0 | ((uint)h1 << 16);
                *(uint*)(Am + off) = (uint)m0 | ((uint)m1 << 16);
                *(uint*)(Al + off) = (uint)l0 | ((uint)l1 << 16);
            }
        }

        // ---- compute: 4 kt (own K-quarter) x 4 nt x 6 products; A-frags read ONCE per kt ----
        f32x4 acc[4] = {{0,0,0,0}, {0,0,0,0}, {0,0,0,0}, {0,0,0,0}};
        #pragma unroll
        for (int j = 0; j < 4; ++j) {
            const uint kl = (uint)((wv * 4 + j) * 32 + koct * 8);
            const uint ao = swz((uint)m, kl);
            s16x8 fh = *(const s16x8*)(mhi ? ZB : (Ah + ao));
            s16x8 fm = *(const s16x8*)(mhi ? ZB : (Am + ao));
            s16x8 fl = *(const s16x8*)(mhi ? ZB : (Al + ao));
            #pragma unroll
            for (int nt = 0; nt < 4; ++nt) {
                s16x8 blf = *(const s16x8*)(Blo + swz((uint)(nt * 16 + m), kl));
                acc[nt] = __builtin_amdgcn_mfma_f32_16x16x32_bf16(fh, bh[nt][j], acc[nt], 0, 0, 0);
                acc[nt] = __builtin_amdgcn_mfma_f32_16x16x32_bf16(fh, bm[nt][j], acc[nt], 0, 0, 0);
                acc[nt] = __builtin_amdgcn_mfma_f32_16x16x32_bf16(fm, bh[nt][j], acc[nt], 0, 0, 0);
                acc[nt] = __builtin_amdgcn_mfma_f32_16x16x32_bf16(fm, bm[nt][j], acc[nt], 0, 0, 0);
                acc[nt] = __builtin_amdgcn_mfma_f32_16x16x32_bf16(fh, blf,       acc[nt], 0, 0, 0);
                acc[nt] = __builtin_amdgcn_mfma_f32_16x16x32_bf16(fl, bh[nt][j], acc[nt], 0, 0, 0);
            }
        }

        // ---- cross-wave K-reduce via double-buffered scratch; ONE barrier per step ----
        float* sb = (float*)(lds + SCR_OFF + (t & 1) * SCR_SZ);
        #pragma unroll
        for (int nt = 0; nt < 4; ++nt)
            *(f32x4*)(sb + ((size_t)(nt * 4 + wv) * 64 + lane) * 4) = acc[nt];
        bar_lds();   // partials(t) ready; also orders scr[t&1] vs t+2 reuse (2-deep safe)

        f32x4 s = {0, 0, 0, 0};
        #pragma unroll
        for (int v = 0; v < 4; ++v)
            s += *(const f32x4*)(sb + ((size_t)(wv * 4 + v) * 64 + lane) * 4);

        // ---- epilogue: relu, sanitize, pair cols via shfl, 8B stores ----
        uint u0 = 0, u1 = 0, u2 = 0, u3 = 0;
        if (doEp) {
            float y0 = fmaxf(s[0] + fmaf(xr[0].x, wxv.x, fmaf(xr[0].y, wxv.y, bq)), 0.f);
            float y1 = fmaxf(s[1] + fmaf(xr[1].x, wxv.x, fmaf(xr[1].y, wxv.y, bq)), 0.f);
            float y2 = fmaxf(s[2] + fmaf(xr[2].x, wxv.x, fmaf(xr[2].y, wxv.y, bq)), 0.f);
            float y3 = fmaxf(s[3] + fmaf(xr[3].x, wxv.x, fmaf(xr[3].y, wxv.y, bq)), 0.f);
            u0 = __float_as_uint(y0); if (u0 == SENT) u0 = 0u;
            u1 = __float_as_uint(y1); if (u1 == SENT) u1 = 0u;
            u2 = __float_as_uint(y2); if (u2 == SENT) u2 = 0u;
            u3 = __float_as_uint(y3); if (u3 == SENT) u3 = 0u;
        }
        uint q0 = (uint)__shfl_xor((int)u0, 1);
        uint q1 = (uint)__shfl_xor((int)u1, 1);
        uint q2 = (uint)__shfl_xor((int)u2, 1);
        uint q3 = (uint)__shfl_xor((int)u3, 1);
        if (doEp && !(lane & 1)) {
            float* obase = out + (size_t)(t + 1) * BATCH * HD;
            __hip_atomic_store((ull*)(obase + (size_t)(gb * 8 + r0 + 0) * HD + col),
                               (ull)u0 | ((ull)q0 << 32), __ATOMIC_RELAXED, __HIP_MEMORY_SCOPE_AGENT);
            __hip_atomic_store((ull*)(obase + (size_t)(gb * 8 + r0 + 1) * HD + col),
                               (ull)u1 | ((ull)q1 << 32), __ATOMIC_RELAXED, __HIP_MEMORY_SCOPE_AGENT);
            __hip_atomic_store((ull*)(obase + (size_t)(gb * 8 + r0 + 2) * HD + col),
                               (ull)u2 | ((ull)q2 << 32), __ATOMIC_RELAXED, __HIP_MEMORY_SCOPE_AGENT);
            __hip_atomic_store((ull*)(obase + (size_t)(gb * 8 + r0 + 3) * HD + col),
                               (ull)u3 | ((ull)q3 << 32), __ATOMIC_RELAXED, __HIP_MEMORY_SCOPE_AGENT);
        }

        if (t + 1 < TT) {
            // issue polls for own 2 chunks of slab t+1 (checked at start of next iter)
            const float* sl = out + (size_t)(t + 1) * BATCH * HD + rowoff;
            #pragma unroll
            for (int j = 0; j < 8; ++j)
                pv[j] = __hip_atomic_load((const ull*)(sl + 2 * j),
                                          __ATOMIC_RELAXED, __HIP_MEMORY_SCOPE_AGENT);
        }
    }
}

extern "C" void kernel_launch(void* const* d_in, const int* in_sizes, int n_in,
                              void* d_out, int out_size, void* d_ws, size_t ws_size,
                              hipStream_t stream) {
    const float* x  = (const float*)d_in[0];
    const float* Wh = (const float*)d_in[1];
    const float* Wx = (const float*)d_in[2];
    const float* bx = (const float*)d_in[3];
    float* out = (float*)d_out;

    (void)hipFuncSetAttribute((const void*)rnn_ksplit_kernel,
                              hipFuncAttributeMaxDynamicSharedMemorySize, LDS_BYTES);

    fill_kernel<<<dim3(4096), dim3(256), 0, stream>>>((uint*)out);
    init_kernel<<<dim3(BATCH * HD / 4 / 256), dim3(256), 0, stream>>>(out);

    void* args[] = { (void*)&x, (void*)&Wh, (void*)&Wx, (void*)&bx, (void*)&out };
    hipError_t ce = hipLaunchCooperativeKernel((const void*)rnn_ksplit_kernel,
                                               dim3(256), dim3(256), args, LDS_BYTES, stream);
    if (ce != hipSuccess) {
        rnn_ksplit_kernel<<<dim3(256), dim3(256), LDS_BYTES, stream>>>(x, Wh, Wx, bx, out);
    }
}